// Round 1
// baseline (383.963 us; speedup 1.0000x reference)
//
#include <hip/hip_runtime.h>
#include <hip/hip_bf16.h>

#define BATCH 4
#define SEQ   4096
#define EMB   1024
#define HS    64

typedef __attribute__((ext_vector_type(4))) short  short4v;
typedef __attribute__((ext_vector_type(4))) float  float4v;
typedef __attribute__((ext_vector_type(8))) unsigned short ushort8v;

// Q pre-scale: 1/sqrt(64) * log2(e) so softmax can use exp2 directly.
#define QSCALE 0.1803368801111204f

static __device__ __forceinline__ unsigned short f2bf(float f){
  __hip_bfloat16 h = __float2bfloat16(f);
  return *reinterpret_cast<unsigned short*>(&h);
}

// D = A*B + C, 16x16x16 bf16 (K=16). Classic gfx90a fragment layout:
//  A: lane l holds A[l%16][4*(l/16)+j], j=0..3
//  B: lane l holds B[4*(l/16)+j][l%16]
//  C/D: lane l holds D[4*(l/16)+reg][l%16]   (verified C/D mapping, m89/m91)
static __device__ __forceinline__ float4v mfma16(short4v a, short4v b, float4v c){
#if __has_builtin(__builtin_amdgcn_mfma_f32_16x16x16bf16_1k)
  return __builtin_amdgcn_mfma_f32_16x16x16bf16_1k(a, b, c, 0, 0, 0);
#else
  float4v d;
  asm("v_mfma_f32_16x16x16_bf16 %0, %1, %2, %3" : "=v"(d) : "v"(a), "v"(b), "v"(c));
  return d;
#endif
}

// ---------------- projection: Q/K/V = x @ W, fp32 compute, bf16 out ----------------
__global__ __launch_bounds__(256) void proj_kernel(
    const float* __restrict__ x,
    const float* __restrict__ Wq, const float* __restrict__ Wk, const float* __restrict__ Wv,
    unsigned short* __restrict__ Qb, unsigned short* __restrict__ Kb, unsigned short* __restrict__ Vb){
  __shared__ float xs[8 * EMB];                      // 32 KB: 8 rows of x
  const int tid = threadIdx.x;
  const size_t row0 = (size_t)blockIdx.x * 8;
  const float4* xg = reinterpret_cast<const float4*>(x + row0 * EMB);
  float4* xsv = reinterpret_cast<float4*>(xs);
  #pragma unroll
  for (int i = 0; i < 8; ++i) xsv[tid + 256 * i] = xg[tid + 256 * i];
  __syncthreads();

  const int h  = tid & 63;
  const int mm = tid >> 6;                           // 0=Q 1=K 2=V, 3 idle
  if (mm < 3){
    const float* W = (mm == 0) ? Wq : (mm == 1) ? Wk : Wv;
    float acc[8] = {0,0,0,0,0,0,0,0};
    for (int e = 0; e < EMB; e += 2){
      const float w0 = W[e * HS + h];
      const float w1 = W[(e + 1) * HS + h];
      #pragma unroll
      for (int r = 0; r < 8; ++r){
        float2 xv = *reinterpret_cast<const float2*>(&xs[r * EMB + e]);
        acc[r] = fmaf(xv.x, w0, acc[r]);
        acc[r] = fmaf(xv.y, w1, acc[r]);
      }
    }
    const float scale = (mm == 0) ? QSCALE : 1.0f;
    unsigned short* Out = (mm == 0) ? Qb : (mm == 1) ? Kb : Vb;
    #pragma unroll
    for (int r = 0; r < 8; ++r) Out[(row0 + r) * HS + h] = f2bf(acc[r] * scale);
  }
}

// ---------------- flash attention, causal, swapped-operand MFMA ----------------
// Block: 128 threads = 2 waves; wave w owns 16 q-rows. Grid: 4 batches * 128 q-blocks.
__global__ __launch_bounds__(128) void attn_kernel(
    const unsigned short* __restrict__ Qb, const unsigned short* __restrict__ Kb,
    const unsigned short* __restrict__ Vb, float* __restrict__ out){
  __shared__ unsigned short Ks[64 * 64];   // K tile,  [key][d]
  __shared__ unsigned short Vt[64 * 64];   // V^T tile,[d][key]
  const int tid  = threadIdx.x;
  const int lane = tid & 63;
  const int w    = tid >> 6;               // wave 0/1
  const int b    = blockIdx.x & 3;
  const int j    = blockIdx.x >> 2;        // 32-row q-block, 0..127
  const int qbase = j * 32 + w * 16;
  const int qmax  = qbase + 15;
  const int ln = lane & 15;                // column index (q) in frags
  const int lg = lane >> 4;                // lane group 0..3

  const size_t base = (size_t)b * SEQ * HS;

  // Q fragments (B operand of S^T = K * Q^T): B[d][q] = Q[q][d]
  short4v qf[4];
  #pragma unroll
  for (int ds = 0; ds < 4; ++ds)
    qf[ds] = *reinterpret_cast<const short4v*>(Qb + base + (size_t)(qbase + ln) * HS + ds * 16 + lg * 4);

  float m = -1e30f, lsum = 0.f;
  float4v oacc[4];
  #pragma unroll
  for (int dt = 0; dt < 4; ++dt) oacc[dt] = (float4v){0.f, 0.f, 0.f, 0.f};

  const int nt = (j * 32 + 32 + 63) >> 6;  // 64-key tiles to cover causal range
  for (int t = 0; t < nt; ++t){
    const int k0 = t * 64;
    // ---- stage K (linear) and V (transposed) into LDS ----
    {
      const int r  = tid >> 1;             // 0..63  (key row)
      const int c0 = (tid & 1) * 32;       // 0 or 32 (d col)
      const ushort8v* kg = reinterpret_cast<const ushort8v*>(Kb + base + (size_t)(k0 + r) * HS + c0);
      ushort8v* ks = reinterpret_cast<ushort8v*>(&Ks[r * 64 + c0]);
      ks[0] = kg[0]; ks[1] = kg[1]; ks[2] = kg[2]; ks[3] = kg[3];
      const ushort8v* vg = reinterpret_cast<const ushort8v*>(Vb + base + (size_t)(k0 + r) * HS + c0);
      #pragma unroll
      for (int g = 0; g < 4; ++g){
        ushort8v vv = vg[g];
        #pragma unroll
        for (int i = 0; i < 8; ++i) Vt[(c0 + g * 8 + i) * 64 + r] = vv[i];
      }
    }
    __syncthreads();

    if (k0 <= qmax){
      // ---- S^T tiles: D[key'][q] += sum_d K[key][d] * Q[q][d] ----
      float4v st[4];
      #pragma unroll
      for (int kt = 0; kt < 4; ++kt){
        float4v acc = (float4v){0.f, 0.f, 0.f, 0.f};
        #pragma unroll
        for (int ds = 0; ds < 4; ++ds){
          short4v a = *reinterpret_cast<const short4v*>(&Ks[(kt * 16 + ln) * 64 + ds * 16 + lg * 4]);
          acc = mfma16(a, qf[ds], acc);
        }
        st[kt] = acc;
      }
      // ---- causal mask (k > q -> -inf) ----
      const int gq = qbase + ln;
      #pragma unroll
      for (int kt = 0; kt < 4; ++kt){
        if (k0 + kt * 16 + 15 > qbase){
          #pragma unroll
          for (int r = 0; r < 4; ++r){
            const int gk = k0 + kt * 16 + lg * 4 + r;
            if (gk > gq) st[kt][r] = -1e30f;
          }
        }
      }
      // ---- online softmax per q column (col = lane&15; 4 lane replicas) ----
      float tmax = -1e30f;
      #pragma unroll
      for (int kt = 0; kt < 4; ++kt)
        #pragma unroll
        for (int r = 0; r < 4; ++r) tmax = fmaxf(tmax, st[kt][r]);
      tmax = fmaxf(tmax, __shfl_xor(tmax, 16, 64));
      tmax = fmaxf(tmax, __shfl_xor(tmax, 32, 64));
      const float mnew = fmaxf(m, tmax);
      const float corr = exp2f(m - mnew);
      float psum = 0.f;
      short4v pb[4];
      #pragma unroll
      for (int kt = 0; kt < 4; ++kt){
        #pragma unroll
        for (int r = 0; r < 4; ++r){
          const float p = exp2f(st[kt][r] - mnew);
          psum += p;
          pb[kt][r] = (short)f2bf(p);
        }
      }
      psum += __shfl_xor(psum, 16, 64);
      psum += __shfl_xor(psum, 32, 64);
      lsum = lsum * corr + psum;
      m = mnew;
      #pragma unroll
      for (int dt = 0; dt < 4; ++dt){
        oacc[dt][0] *= corr; oacc[dt][1] *= corr; oacc[dt][2] *= corr; oacc[dt][3] *= corr;
      }
      // ---- O^T += V^T * P^T : A = V^T frag from Vt, B = pb (C/D layout == B layout) ----
      #pragma unroll
      for (int dt = 0; dt < 4; ++dt){
        #pragma unroll
        for (int kt = 0; kt < 4; ++kt){
          short4v a = *reinterpret_cast<const short4v*>(&Vt[(dt * 16 + ln) * 64 + kt * 16 + lg * 4]);
          oacc[dt] = mfma16(a, pb[kt], oacc[dt]);
        }
      }
    }
    __syncthreads();
  }

  // ---- epilogue: out[b][q][d] = O^T[d][q] / lsum ----
  const float inv = 1.0f / lsum;
  float* ob = out + base;
  #pragma unroll
  for (int dt = 0; dt < 4; ++dt)
    #pragma unroll
    for (int r = 0; r < 4; ++r)
      ob[(size_t)(qbase + ln) * HS + dt * 16 + lg * 4 + r] = oacc[dt][r] * inv;
}

extern "C" void kernel_launch(void* const* d_in, const int* in_sizes, int n_in,
                              void* d_out, int out_size, void* d_ws, size_t ws_size,
                              hipStream_t stream){
  const float* x  = (const float*)d_in[0];
  const float* Wq = (const float*)d_in[1];
  const float* Wk = (const float*)d_in[2];
  const float* Wv = (const float*)d_in[3];
  // workspace: Q,K,V bf16 [4][4096][64] = 3 * 2 MB = 6 MB
  unsigned short* Qb = (unsigned short*)d_ws;
  unsigned short* Kb = Qb + (size_t)BATCH * SEQ * HS;
  unsigned short* Vb = Kb + (size_t)BATCH * SEQ * HS;

  proj_kernel<<<BATCH * SEQ / 8, 256, 0, stream>>>(x, Wq, Wk, Wv, Qb, Kb, Vb);
  attn_kernel<<<BATCH * (SEQ / 32), 128, 0, stream>>>(Qb, Kb, Vb, (float*)d_out);
}

// Round 2
// 204.630 us; speedup vs baseline: 1.8764x; 1.8764x over previous
//
#include <hip/hip_runtime.h>
#include <hip/hip_bf16.h>

#define BATCH 4
#define SEQ   4096
#define EMB   1024
#define HS    64

typedef __attribute__((ext_vector_type(4))) short  short4v;
typedef __attribute__((ext_vector_type(4))) float  float4v;
typedef __attribute__((ext_vector_type(8))) unsigned short ushort8v;

// Q pre-scale: 1/sqrt(64) * log2(e) so softmax can use exp2 directly.
#define QSCALE 0.1803368801111204f

static __device__ __forceinline__ unsigned short f2bf(float f){
  __hip_bfloat16 h = __float2bfloat16(f);
  return *reinterpret_cast<unsigned short*>(&h);
}

// D = A*B + C, 16x16x16 bf16 (K=16).
//  A: lane l holds A[l%16][4*(l/16)+j], j=0..3
//  B: lane l holds B[4*(l/16)+j][l%16]
//  C/D: lane l holds D[4*(l/16)+reg][l%16]
static __device__ __forceinline__ float4v mfma16(short4v a, short4v b, float4v c){
#if __has_builtin(__builtin_amdgcn_mfma_f32_16x16x16bf16_1k)
  return __builtin_amdgcn_mfma_f32_16x16x16bf16_1k(a, b, c, 0, 0, 0);
#else
  float4v d;
  asm("v_mfma_f32_16x16x16_bf16 %0, %1, %2, %3" : "=v"(d) : "v"(a), "v"(b), "v"(c));
  return d;
#endif
}

// ---------------- projection: Q/K = x @ W row-major bf16, V emitted TRANSPOSED ----------------
// Vt layout: [d=64][BATCH*SEQ]  (Vt[d][b*SEQ+s] = V[b][s][d])
__global__ __launch_bounds__(256) void proj_kernel(
    const float* __restrict__ x,
    const float* __restrict__ Wq, const float* __restrict__ Wk, const float* __restrict__ Wv,
    unsigned short* __restrict__ Qb, unsigned short* __restrict__ Kb, unsigned short* __restrict__ Vt){
  __shared__ float xs[8 * EMB];                      // 32 KB: 8 rows of x
  const int tid = threadIdx.x;
  const size_t row0 = (size_t)blockIdx.x * 8;
  const float4* xg = reinterpret_cast<const float4*>(x + row0 * EMB);
  float4* xsv = reinterpret_cast<float4*>(xs);
  #pragma unroll
  for (int i = 0; i < 8; ++i) xsv[tid + 256 * i] = xg[tid + 256 * i];
  __syncthreads();

  const int h  = tid & 63;
  const int mm = tid >> 6;                           // 0=Q 1=K 2=V, 3 idle
  if (mm < 3){
    const float* W = (mm == 0) ? Wq : (mm == 1) ? Wk : Wv;
    float acc[8] = {0,0,0,0,0,0,0,0};
    for (int e = 0; e < EMB; e += 2){
      const float w0 = W[e * HS + h];
      const float w1 = W[(e + 1) * HS + h];
      #pragma unroll
      for (int r = 0; r < 8; ++r){
        float2 xv = *reinterpret_cast<const float2*>(&xs[r * EMB + e]);
        acc[r] = fmaf(xv.x, w0, acc[r]);
        acc[r] = fmaf(xv.y, w1, acc[r]);
      }
    }
    if (mm == 2){
      // V transposed: one packed 16B store of 8 consecutive seq positions
      ushort8v pk;
      #pragma unroll
      for (int r = 0; r < 8; ++r) pk[r] = f2bf(acc[r]);
      *reinterpret_cast<ushort8v*>(Vt + (size_t)h * (BATCH * SEQ) + row0) = pk;
    } else {
      const float scale = (mm == 0) ? QSCALE : 1.0f;
      unsigned short* Out = (mm == 0) ? Qb : Kb;
      #pragma unroll
      for (int r = 0; r < 8; ++r) Out[(row0 + r) * HS + h] = f2bf(acc[r] * scale);
    }
  }
}

// ---------------- flash attention partials, causal, kv-split ----------------
// Block: 256 threads = 4 waves; wave w owns 16 q-rows (block: 64 rows).
// Chunked over keys: chunk c covers keys [c*CHUNK, min((c+1)*CHUNK, qend)).
// LDS rows padded to 72 ushorts (144B = 36 dwords) -> conflict-free b64 reads.
template<int CHUNK>
__global__ __launch_bounds__(256) void attn_partial(
    const unsigned short* __restrict__ Qb, const unsigned short* __restrict__ Kb,
    const unsigned short* __restrict__ Vt,
    float* __restrict__ Opart, float* __restrict__ Mpart, float* __restrict__ Lpart){
  constexpr int GS  = CHUNK / 64;                 // 64-row q-blocks per chunk group
  constexpr int NG  = SEQ / CHUNK;                // number of key chunks
  constexpr int PCB = GS * NG * (NG + 1) / 2;     // partials per batch
  constexpr int LDP = 72;                         // padded row, ushorts

  __shared__ unsigned short Ks[64 * LDP];
  __shared__ unsigned short Vs[64 * LDP];

  // ---- decode blockIdx -> (b, qj, c) ----
  const int b = blockIdx.x / PCB;
  const int g = blockIdx.x % PCB;
  int a = 0, accb = 0;
  while (g >= accb + GS * (a + 1)) { accb += GS * (a + 1); ++a; }   // <= NG-1 iters
  const int rem = g - accb;
  const int qj  = a * GS + rem / (a + 1);          // 64-row q-block index
  const int c   = rem % (a + 1);                   // key chunk index

  const int tid  = threadIdx.x;
  const int lane = tid & 63;
  const int w    = tid >> 6;
  const int ln   = lane & 15;
  const int lg   = lane >> 4;

  const size_t bbase = (size_t)b * SEQ * HS;
  const int qbase  = qj * 64 + w * 16;
  const int cstart = c * CHUNK;
  const int kend   = min(cstart + CHUNK, qj * 64 + 64);   // always multiple of 64
  const int nt     = (kend - cstart) >> 6;

  // Q fragments (B operand of S^T): B[d][q] = Q[q][d]
  short4v qf[4];
  #pragma unroll
  for (int ds = 0; ds < 4; ++ds)
    qf[ds] = *reinterpret_cast<const short4v*>(Qb + bbase + (size_t)(qbase + ln) * HS + ds * 16 + lg * 4);

  float m = -1e30f, lsum = 0.f;
  float4v oacc[4];
  #pragma unroll
  for (int dt = 0; dt < 4; ++dt) oacc[dt] = (float4v){0.f, 0.f, 0.f, 0.f};

  // ---- staging (reg-prefetch, single LDS buffer) ----
  const int srow = tid >> 2;                       // 0..63
  const int sseg = tid & 3;                        // 16-ushort segment
  const unsigned short* Kg = Kb + bbase + (size_t)(cstart + srow) * HS + sseg * 16;
  const unsigned short* Vg = Vt + (size_t)srow * (BATCH * SEQ) + b * SEQ + cstart + sseg * 16;
  ushort8v kr0, kr1, vr0, vr1;
  kr0 = reinterpret_cast<const ushort8v*>(Kg)[0];
  kr1 = reinterpret_cast<const ushort8v*>(Kg)[1];
  vr0 = reinterpret_cast<const ushort8v*>(Vg)[0];
  vr1 = reinterpret_cast<const ushort8v*>(Vg)[1];

  for (int t = 0; t < nt; ++t){
    // write staged regs to LDS
    *reinterpret_cast<ushort8v*>(&Ks[srow * LDP + sseg * 16])     = kr0;
    *reinterpret_cast<ushort8v*>(&Ks[srow * LDP + sseg * 16 + 8]) = kr1;
    *reinterpret_cast<ushort8v*>(&Vs[srow * LDP + sseg * 16])     = vr0;
    *reinterpret_cast<ushort8v*>(&Vs[srow * LDP + sseg * 16 + 8]) = vr1;
    __syncthreads();
    // prefetch next tile (overlaps compute below)
    if (t + 1 < nt){
      const unsigned short* Kn = Kg + (size_t)(t + 1) * 64 * HS;
      const unsigned short* Vn = Vg + (t + 1) * 64;
      kr0 = reinterpret_cast<const ushort8v*>(Kn)[0];
      kr1 = reinterpret_cast<const ushort8v*>(Kn)[1];
      vr0 = reinterpret_cast<const ushort8v*>(Vn)[0];
      vr1 = reinterpret_cast<const ushort8v*>(Vn)[1];
    }

    const int k0 = cstart + t * 64;
    if (k0 <= qbase + 15){
      // ---- S^T tiles ----
      float4v st[4];
      #pragma unroll
      for (int kt = 0; kt < 4; ++kt){
        float4v acc = (float4v){0.f, 0.f, 0.f, 0.f};
        #pragma unroll
        for (int ds = 0; ds < 4; ++ds){
          short4v av = *reinterpret_cast<const short4v*>(&Ks[(kt * 16 + ln) * LDP + ds * 16 + lg * 4]);
          acc = mfma16(av, qf[ds], acc);
        }
        st[kt] = acc;
      }
      // ---- causal mask ----
      const int gq = qbase + ln;
      #pragma unroll
      for (int kt = 0; kt < 4; ++kt){
        if (k0 + kt * 16 + 15 > qbase){
          #pragma unroll
          for (int r = 0; r < 4; ++r){
            const int gk = k0 + kt * 16 + lg * 4 + r;
            if (gk > gq) st[kt][r] = -1e30f;
          }
        }
      }
      // ---- online softmax (per q column; 4 lane replicas over lg) ----
      float tmax = -1e30f;
      #pragma unroll
      for (int kt = 0; kt < 4; ++kt)
        #pragma unroll
        for (int r = 0; r < 4; ++r) tmax = fmaxf(tmax, st[kt][r]);
      tmax = fmaxf(tmax, __shfl_xor(tmax, 16, 64));
      tmax = fmaxf(tmax, __shfl_xor(tmax, 32, 64));
      const float mnew = fmaxf(m, tmax);
      const float corr = exp2f(m - mnew);
      float psum = 0.f;
      short4v pb[4];
      #pragma unroll
      for (int kt = 0; kt < 4; ++kt){
        #pragma unroll
        for (int r = 0; r < 4; ++r){
          const float p = exp2f(st[kt][r] - mnew);
          psum += p;
          pb[kt][r] = (short)f2bf(p);
        }
      }
      psum += __shfl_xor(psum, 16, 64);
      psum += __shfl_xor(psum, 32, 64);
      lsum = lsum * corr + psum;
      m = mnew;
      #pragma unroll
      for (int dt = 0; dt < 4; ++dt){
        oacc[dt][0] *= corr; oacc[dt][1] *= corr; oacc[dt][2] *= corr; oacc[dt][3] *= corr;
      }
      // ---- O^T += V^T * P^T ----
      #pragma unroll
      for (int dt = 0; dt < 4; ++dt){
        #pragma unroll
        for (int kt = 0; kt < 4; ++kt){
          short4v av = *reinterpret_cast<const short4v*>(&Vs[(dt * 16 + ln) * LDP + kt * 16 + lg * 4]);
          oacc[dt] = mfma16(av, pb[kt], oacc[dt]);
        }
      }
    }
    __syncthreads();
  }

  // ---- write partial (unnormalized O, running m, l) ----
  const int p = b * PCB + g;
  const int ql = w * 16 + ln;
  float* Op = Opart + ((size_t)p * 64 + ql) * 64;
  #pragma unroll
  for (int dt = 0; dt < 4; ++dt)
    *reinterpret_cast<float4v*>(Op + dt * 16 + lg * 4) = oacc[dt];
  if (lg == 0){
    Mpart[p * 64 + ql] = m;
    Lpart[p * 64 + ql] = lsum;
  }
}

// ---------------- combine partials ----------------
template<int CHUNK>
__global__ __launch_bounds__(256) void combine_kernel(
    const float* __restrict__ Opart, const float* __restrict__ Mpart,
    const float* __restrict__ Lpart, float* __restrict__ out){
  constexpr int GS  = CHUNK / 64;
  constexpr int NG  = SEQ / CHUNK;
  constexpr int PCB = GS * NG * (NG + 1) / 2;
  const int gid = blockIdx.x * 4 + (threadIdx.x >> 6);   // global row 0..16383
  const int d   = threadIdx.x & 63;
  const int b   = gid >> 12;
  const int q   = gid & (SEQ - 1);
  const int qj  = q >> 6;
  const int a   = qj / GS;
  const int nch = a + 1;
  const int p0  = b * PCB + GS * a * (a + 1) / 2 + (qj - a * GS) * (a + 1);
  const int ql  = q & 63;

  float M = -1e30f;
  for (int cc = 0; cc < nch; ++cc) M = fmaxf(M, Mpart[(p0 + cc) * 64 + ql]);
  float L = 0.f, O = 0.f;
  for (int cc = 0; cc < nch; ++cc){
    const float s = exp2f(Mpart[(p0 + cc) * 64 + ql] - M);
    L += s * Lpart[(p0 + cc) * 64 + ql];
    O += s * Opart[((size_t)(p0 + cc) * 64 + ql) * 64 + d];
  }
  out[(size_t)gid * 64 + d] = O / L;
}

extern "C" void kernel_launch(void* const* d_in, const int* in_sizes, int n_in,
                              void* d_out, int out_size, void* d_ws, size_t ws_size,
                              hipStream_t stream){
  const float* x  = (const float*)d_in[0];
  const float* Wq = (const float*)d_in[1];
  const float* Wk = (const float*)d_in[2];
  const float* Wv = (const float*)d_in[3];

  const size_t nqkv = (size_t)BATCH * SEQ * HS;
  unsigned short* Qb = (unsigned short*)d_ws;
  unsigned short* Kb = Qb + nqkv;
  unsigned short* Vt = Kb + nqkv;                 // [HS][BATCH*SEQ]
  float* scratch = (float*)(Vt + nqkv);           // 6 MB in

  proj_kernel<<<BATCH * SEQ / 8, 256, 0, stream>>>(x, Wq, Wk, Wv, Qb, Kb, Vt);

  // choose split by workspace capacity
  constexpr int PCB1 = (1024/64) * (SEQ/1024) * ((SEQ/1024) + 1) / 2;   // 160
  constexpr int PCB4 = (4096/64) * (SEQ/4096) * ((SEQ/4096) + 1) / 2;   // 64
  const size_t need1 = 6 * nqkv / 3 * 1 /*qkv bytes*/ ; // (placeholder, computed below)
  (void)need1;
  const size_t base_bytes = 3 * nqkv * sizeof(unsigned short);
  const size_t part1 = (size_t)BATCH * PCB1 * 64 * (64 + 2) * sizeof(float);
  const size_t part4 = (size_t)BATCH * PCB4 * 64 * (64 + 2) * sizeof(float);

  if (ws_size >= base_bytes + part1){
    float* Opart = scratch;
    float* Mpart = Opart + (size_t)BATCH * PCB1 * 64 * 64;
    float* Lpart = Mpart + (size_t)BATCH * PCB1 * 64;
    attn_partial<1024><<<BATCH * PCB1, 256, 0, stream>>>(Qb, Kb, Vt, Opart, Mpart, Lpart);
    combine_kernel<1024><<<BATCH * SEQ / 4, 256, 0, stream>>>(Opart, Mpart, Lpart, (float*)d_out);
  } else {
    (void)part4;
    float* Opart = scratch;
    float* Mpart = Opart + (size_t)BATCH * PCB4 * 64 * 64;
    float* Lpart = Mpart + (size_t)BATCH * PCB4 * 64;
    attn_partial<4096><<<BATCH * PCB4, 256, 0, stream>>>(Qb, Kb, Vt, Opart, Mpart, Lpart);
    combine_kernel<4096><<<BATCH * SEQ / 4, 256, 0, stream>>>(Opart, Mpart, Lpart, (float*)d_out);
  }
}

// Round 3
// 96.220 us; speedup vs baseline: 3.9905x; 2.1267x over previous
//
#include <hip/hip_runtime.h>
#include <hip/hip_bf16.h>

#define BATCH 4
#define SEQ   4096
#define EMB   1024
#define HS    64

typedef __attribute__((ext_vector_type(4))) short  short4v;
typedef __attribute__((ext_vector_type(4))) float  float4v;
typedef __attribute__((ext_vector_type(8))) unsigned short ushort8v;

// Q pre-scale: 1/sqrt(64) * log2(e) so softmax can use exp2 directly.
#define QSCALE 0.1803368801111204f

static __device__ __forceinline__ unsigned short f2bf(float f){
  __hip_bfloat16 h = __float2bfloat16(f);
  return *reinterpret_cast<unsigned short*>(&h);
}

// D = A*B + C, 16x16x16 bf16 (K=16).
//  A: lane l holds A[l%16][4*(l/16)+j], j=0..3
//  B: lane l holds B[4*(l/16)+j][l%16]
//  C/D: lane l holds D[4*(l/16)+reg][l%16]
static __device__ __forceinline__ float4v mfma16(short4v a, short4v b, float4v c){
#if __has_builtin(__builtin_amdgcn_mfma_f32_16x16x16bf16_1k)
  return __builtin_amdgcn_mfma_f32_16x16x16bf16_1k(a, b, c, 0, 0, 0);
#else
  float4v d;
  asm("v_mfma_f32_16x16x16_bf16 %0, %1, %2, %3" : "=v"(d) : "v"(a), "v"(b), "v"(c));
  return d;
#endif
}

// ---------------- W pack: fp32 [1024][64] x3 -> bf16 fragment-major ----------------
// Wpack[kstep][ks][nt][lane][j]  (16*4*12*64*4 ushorts = 384 KB)
//   holds B[k][n], k = kstep*64 + ks*16 + (lane>>4)*4 + j, n = nt*16 + (lane&15)
//   nt 0..3 -> Q (scaled by QSCALE), 4..7 -> K, 8..11 -> V
__global__ __launch_bounds__(256) void pack_kernel(
    const float* __restrict__ Wq, const float* __restrict__ Wk, const float* __restrict__ Wv,
    unsigned short* __restrict__ Wpack){
  const int flat = blockIdx.x * 256 + threadIdx.x;       // 0..49151
  const int lane = flat & 63;
  const int f    = flat >> 6;
  const int nt   = f % 12;
  const int ks   = (f / 12) & 3;
  const int kstep= f / 48;
  const int k0   = kstep * 64 + ks * 16 + (lane >> 4) * 4;
  const int h    = (nt & 3) * 16 + (lane & 15);
  const int mat  = nt >> 2;
  const float* W = (mat == 0) ? Wq : (mat == 1) ? Wk : Wv;
  const float scale = (mat == 0) ? QSCALE : 1.0f;
  short4v pk;
  #pragma unroll
  for (int j = 0; j < 4; ++j) pk[j] = (short)f2bf(W[(size_t)(k0 + j) * HS + h] * scale);
  *reinterpret_cast<short4v*>(Wpack + (size_t)flat * 4) = pk;
}

// ---------------- projection GEMM: LDS-free MFMA ----------------
// Grid 256 blocks x 4 waves. Wave w owns 16 rows (grow0..+15) x 192 cols.
__global__ __launch_bounds__(256) void proj_mfma(
    const float* __restrict__ x, const unsigned short* __restrict__ Wpack,
    unsigned short* __restrict__ Qb, unsigned short* __restrict__ Kb,
    unsigned short* __restrict__ Vt){
  const int tid  = threadIdx.x;
  const int lane = tid & 63;
  const int w    = tid >> 6;
  const int ln   = lane & 15;
  const int lg   = lane >> 4;
  const int grow0 = blockIdx.x * 64 + w * 16;

  float4v acc[12];
  #pragma unroll
  for (int nt = 0; nt < 12; ++nt) acc[nt] = (float4v){0.f, 0.f, 0.f, 0.f};

  const float* xrow = x + (size_t)(grow0 + ln) * EMB + lg * 4;   // lane's A rows/cols
  const unsigned short* wp = Wpack + lane * 4;

  #pragma unroll 4
  for (int kstep = 0; kstep < 16; ++kstep){
    // A fragments: per-lane 16B fp32 load + bf16 convert
    short4v af[4];
    #pragma unroll
    for (int ks = 0; ks < 4; ++ks){
      float4 xv = *reinterpret_cast<const float4*>(xrow + kstep * 64 + ks * 16);
      short4v a;
      a[0] = (short)f2bf(xv.x); a[1] = (short)f2bf(xv.y);
      a[2] = (short)f2bf(xv.z); a[3] = (short)f2bf(xv.w);
      af[ks] = a;
    }
    // B fragments straight from L1/L2-resident Wpack (lane-linear 8B loads)
    #pragma unroll
    for (int nt = 0; nt < 12; ++nt){
      #pragma unroll
      for (int ks = 0; ks < 4; ++ks){
        short4v bf = *reinterpret_cast<const short4v*>(wp + (size_t)((kstep * 4 + ks) * 12 + nt) * 256);
        acc[nt] = mfma16(af[ks], bf, acc[nt]);
      }
    }
  }

  // ---- epilogue: D[4*lg+r][ln] per tile ----
  const int row0 = grow0 + 4 * lg;
  #pragma unroll
  for (int nt = 0; nt < 4; ++nt){
    #pragma unroll
    for (int r = 0; r < 4; ++r){
      Qb[(size_t)(row0 + r) * HS + nt * 16 + ln] = f2bf(acc[nt][r]);
      Kb[(size_t)(row0 + r) * HS + nt * 16 + ln] = f2bf(acc[nt + 4][r]);
    }
  }
  #pragma unroll
  for (int nt = 8; nt < 12; ++nt){
    short4v pk;
    #pragma unroll
    for (int r = 0; r < 4; ++r) pk[r] = (short)f2bf(acc[nt][r]);
    *reinterpret_cast<short4v*>(Vt + (size_t)((nt - 8) * 16 + ln) * (BATCH * SEQ) + row0) = pk;
  }
}

// ---------------- flash attention partials, causal, kv-split ----------------
template<int CHUNK>
__global__ __launch_bounds__(256) void attn_partial(
    const unsigned short* __restrict__ Qb, const unsigned short* __restrict__ Kb,
    const unsigned short* __restrict__ Vt,
    float* __restrict__ Opart, float* __restrict__ Mpart, float* __restrict__ Lpart){
  constexpr int GS  = CHUNK / 64;
  constexpr int NG  = SEQ / CHUNK;
  constexpr int PCB = GS * NG * (NG + 1) / 2;
  constexpr int LDP = 72;

  __shared__ unsigned short Ks[64 * LDP];
  __shared__ unsigned short Vs[64 * LDP];

  const int b = blockIdx.x / PCB;
  const int g = blockIdx.x % PCB;
  int a = 0, accb = 0;
  while (g >= accb + GS * (a + 1)) { accb += GS * (a + 1); ++a; }
  const int rem = g - accb;
  const int qj  = a * GS + rem / (a + 1);
  const int c   = rem % (a + 1);

  const int tid  = threadIdx.x;
  const int lane = tid & 63;
  const int w    = tid >> 6;
  const int ln   = lane & 15;
  const int lg   = lane >> 4;

  const size_t bbase = (size_t)b * SEQ * HS;
  const int qbase  = qj * 64 + w * 16;
  const int cstart = c * CHUNK;
  const int kend   = min(cstart + CHUNK, qj * 64 + 64);
  const int nt     = (kend - cstart) >> 6;

  short4v qf[4];
  #pragma unroll
  for (int ds = 0; ds < 4; ++ds)
    qf[ds] = *reinterpret_cast<const short4v*>(Qb + bbase + (size_t)(qbase + ln) * HS + ds * 16 + lg * 4);

  float m = -1e30f, lsum = 0.f;
  float4v oacc[4];
  #pragma unroll
  for (int dt = 0; dt < 4; ++dt) oacc[dt] = (float4v){0.f, 0.f, 0.f, 0.f};

  const int srow = tid >> 2;
  const int sseg = tid & 3;
  const unsigned short* Kg = Kb + bbase + (size_t)(cstart + srow) * HS + sseg * 16;
  const unsigned short* Vg = Vt + (size_t)srow * (BATCH * SEQ) + b * SEQ + cstart + sseg * 16;
  ushort8v kr0, kr1, vr0, vr1;
  kr0 = reinterpret_cast<const ushort8v*>(Kg)[0];
  kr1 = reinterpret_cast<const ushort8v*>(Kg)[1];
  vr0 = reinterpret_cast<const ushort8v*>(Vg)[0];
  vr1 = reinterpret_cast<const ushort8v*>(Vg)[1];

  for (int t = 0; t < nt; ++t){
    *reinterpret_cast<ushort8v*>(&Ks[srow * LDP + sseg * 16])     = kr0;
    *reinterpret_cast<ushort8v*>(&Ks[srow * LDP + sseg * 16 + 8]) = kr1;
    *reinterpret_cast<ushort8v*>(&Vs[srow * LDP + sseg * 16])     = vr0;
    *reinterpret_cast<ushort8v*>(&Vs[srow * LDP + sseg * 16 + 8]) = vr1;
    __syncthreads();
    if (t + 1 < nt){
      const unsigned short* Kn = Kg + (size_t)(t + 1) * 64 * HS;
      const unsigned short* Vn = Vg + (t + 1) * 64;
      kr0 = reinterpret_cast<const ushort8v*>(Kn)[0];
      kr1 = reinterpret_cast<const ushort8v*>(Kn)[1];
      vr0 = reinterpret_cast<const ushort8v*>(Vn)[0];
      vr1 = reinterpret_cast<const ushort8v*>(Vn)[1];
    }

    const int k0 = cstart + t * 64;
    if (k0 <= qbase + 15){
      float4v st[4];
      #pragma unroll
      for (int kt = 0; kt < 4; ++kt){
        float4v accv = (float4v){0.f, 0.f, 0.f, 0.f};
        #pragma unroll
        for (int ds = 0; ds < 4; ++ds){
          short4v av = *reinterpret_cast<const short4v*>(&Ks[(kt * 16 + ln) * LDP + ds * 16 + lg * 4]);
          accv = mfma16(av, qf[ds], accv);
        }
        st[kt] = accv;
      }
      const int gq = qbase + ln;
      #pragma unroll
      for (int kt = 0; kt < 4; ++kt){
        if (k0 + kt * 16 + 15 > qbase){
          #pragma unroll
          for (int r = 0; r < 4; ++r){
            const int gk = k0 + kt * 16 + lg * 4 + r;
            if (gk > gq) st[kt][r] = -1e30f;
          }
        }
      }
      float tmax = -1e30f;
      #pragma unroll
      for (int kt = 0; kt < 4; ++kt)
        #pragma unroll
        for (int r = 0; r < 4; ++r) tmax = fmaxf(tmax, st[kt][r]);
      tmax = fmaxf(tmax, __shfl_xor(tmax, 16, 64));
      tmax = fmaxf(tmax, __shfl_xor(tmax, 32, 64));
      const float mnew = fmaxf(m, tmax);
      const float corr = exp2f(m - mnew);
      float psum = 0.f;
      short4v pb[4];
      #pragma unroll
      for (int kt = 0; kt < 4; ++kt){
        #pragma unroll
        for (int r = 0; r < 4; ++r){
          const float p = exp2f(st[kt][r] - mnew);
          psum += p;
          pb[kt][r] = (short)f2bf(p);
        }
      }
      psum += __shfl_xor(psum, 16, 64);
      psum += __shfl_xor(psum, 32, 64);
      lsum = lsum * corr + psum;
      m = mnew;
      #pragma unroll
      for (int dt = 0; dt < 4; ++dt){
        oacc[dt][0] *= corr; oacc[dt][1] *= corr; oacc[dt][2] *= corr; oacc[dt][3] *= corr;
      }
      #pragma unroll
      for (int dt = 0; dt < 4; ++dt){
        #pragma unroll
        for (int kt = 0; kt < 4; ++kt){
          short4v av = *reinterpret_cast<const short4v*>(&Vs[(dt * 16 + ln) * LDP + kt * 16 + lg * 4]);
          oacc[dt] = mfma16(av, pb[kt], oacc[dt]);
        }
      }
    }
    __syncthreads();
  }

  const int p = b * PCB + g;
  const int ql = w * 16 + ln;
  float* Op = Opart + ((size_t)p * 64 + ql) * 64;
  #pragma unroll
  for (int dt = 0; dt < 4; ++dt)
    *reinterpret_cast<float4v*>(Op + dt * 16 + lg * 4) = oacc[dt];
  if (lg == 0){
    Mpart[p * 64 + ql] = m;
    Lpart[p * 64 + ql] = lsum;
  }
}

// ---------------- combine partials ----------------
template<int CHUNK>
__global__ __launch_bounds__(256) void combine_kernel(
    const float* __restrict__ Opart, const float* __restrict__ Mpart,
    const float* __restrict__ Lpart, float* __restrict__ out){
  constexpr int GS  = CHUNK / 64;
  constexpr int NG  = SEQ / CHUNK;
  constexpr int PCB = GS * NG * (NG + 1) / 2;
  const int gid = blockIdx.x * 4 + (threadIdx.x >> 6);
  const int d   = threadIdx.x & 63;
  const int b   = gid >> 12;
  const int q   = gid & (SEQ - 1);
  const int qj  = q >> 6;
  const int a   = qj / GS;
  const int nch = a + 1;
  const int p0  = b * PCB + GS * a * (a + 1) / 2 + (qj - a * GS) * (a + 1);
  const int ql  = q & 63;

  float M = -1e30f;
  for (int cc = 0; cc < nch; ++cc) M = fmaxf(M, Mpart[(p0 + cc) * 64 + ql]);
  float L = 0.f, O = 0.f;
  for (int cc = 0; cc < nch; ++cc){
    const float s = exp2f(Mpart[(p0 + cc) * 64 + ql] - M);
    L += s * Lpart[(p0 + cc) * 64 + ql];
    O += s * Opart[((size_t)(p0 + cc) * 64 + ql) * 64 + d];
  }
  out[(size_t)gid * 64 + d] = O / L;
}

extern "C" void kernel_launch(void* const* d_in, const int* in_sizes, int n_in,
                              void* d_out, int out_size, void* d_ws, size_t ws_size,
                              hipStream_t stream){
  const float* x  = (const float*)d_in[0];
  const float* Wq = (const float*)d_in[1];
  const float* Wk = (const float*)d_in[2];
  const float* Wv = (const float*)d_in[3];

  const size_t nqkv = (size_t)BATCH * SEQ * HS;
  unsigned short* Qb = (unsigned short*)d_ws;
  unsigned short* Kb = Qb + nqkv;
  unsigned short* Vt = Kb + nqkv;                     // [HS][BATCH*SEQ]
  unsigned short* Wpack = Vt + nqkv;                  // 196608 ushorts = 384 KB
  float* scratch = (float*)(Wpack + (size_t)16 * 4 * 12 * 64 * 4);

  pack_kernel<<<192, 256, 0, stream>>>(Wq, Wk, Wv, Wpack);
  proj_mfma<<<(BATCH * SEQ) / 64, 256, 0, stream>>>(x, Wpack, Qb, Kb, Vt);

  constexpr int PCB1 = (1024/64) * (SEQ/1024) * ((SEQ/1024) + 1) / 2;   // 160
  constexpr int PCB4 = (4096/64) * (SEQ/4096) * ((SEQ/4096) + 1) / 2;   // 64
  const size_t base_bytes = (3 * nqkv + (size_t)196608) * sizeof(unsigned short);
  const size_t part1 = (size_t)BATCH * PCB1 * 64 * (64 + 2) * sizeof(float);

  if (ws_size >= base_bytes + part1){
    float* Opart = scratch;
    float* Mpart = Opart + (size_t)BATCH * PCB1 * 64 * 64;
    float* Lpart = Mpart + (size_t)BATCH * PCB1 * 64;
    attn_partial<1024><<<BATCH * PCB1, 256, 0, stream>>>(Qb, Kb, Vt, Opart, Mpart, Lpart);
    combine_kernel<1024><<<BATCH * SEQ / 4, 256, 0, stream>>>(Opart, Mpart, Lpart, (float*)d_out);
  } else {
    float* Opart = scratch;
    float* Mpart = Opart + (size_t)BATCH * PCB4 * 64 * 64;
    float* Lpart = Mpart + (size_t)BATCH * PCB4 * 64;
    attn_partial<4096><<<BATCH * PCB4, 256, 0, stream>>>(Qb, Kb, Vt, Opart, Mpart, Lpart);
    combine_kernel<4096><<<BATCH * SEQ / 4, 256, 0, stream>>>(Opart, Mpart, Lpart, (float*)d_out);
  }
}